// Round 1
// baseline (235.365 us; speedup 1.0000x reference)
//
#include <hip/hip_runtime.h>
#include <hip/hip_bf16.h>

typedef __attribute__((ext_vector_type(8))) short short8;
typedef __attribute__((ext_vector_type(4))) float f32x4;
typedef __attribute__((ext_vector_type(4))) int int4v;

#define B_   16
#define O_   512
#define C_   512
#define T_   4096
#define KT   5
#define BM   128
#define BN   128
#define BK   32
#define AST  40   // a_lds row stride in bf16 (32 + 8 pad -> 80B rows, 16B aligned)
#define BST  40
#define NCHUNK (C_/BK)

// ---------------- weight repack: w[o][c][n] f32 -> Wb[n][o][c] bf16 ----------------
__global__ void wrepack_kernel(const float* __restrict__ w, unsigned short* __restrict__ wb) {
    int e = blockIdx.x * 256 + threadIdx.x;
    if (e >= KT * O_ * C_) return;
    int n   = e / (O_ * C_);
    int rem = e % (O_ * C_);
    int o   = rem / C_;
    int c   = rem % C_;
    float v = w[((size_t)o * C_ + c) * KT + n];
    __hip_bfloat16 h = __float2bfloat16(v);
    wb[e] = *reinterpret_cast<unsigned short*>(&h);
}

// ---------------- x transpose: x[b][c][t] f32 -> xT[b][t][c] bf16 ----------------
__global__ void xtrans_kernel(const float* __restrict__ x, unsigned short* __restrict__ xt) {
    __shared__ float tile[64][65];
    int b  = blockIdx.z;
    int c0 = blockIdx.y * 64;
    int t0 = blockIdx.x * 64;
    const float* xb = x + ((size_t)b * C_ + c0) * T_ + t0;
#pragma unroll
    for (int p = 0; p < 4; ++p) {
        int idx = p * 256 + threadIdx.x;
        int cl = idx >> 4;           // 0..63  channel row
        int tj = (idx & 15) << 2;    // 0..60  t col (x4)
        float4 v = *reinterpret_cast<const float4*>(xb + (size_t)cl * T_ + tj);
        tile[cl][tj + 0] = v.x;
        tile[cl][tj + 1] = v.y;
        tile[cl][tj + 2] = v.z;
        tile[cl][tj + 3] = v.w;
    }
    __syncthreads();
    unsigned short* xtb = xt + ((size_t)b * T_ + t0) * C_ + c0;
#pragma unroll
    for (int p = 0; p < 2; ++p) {
        int g  = p * 256 + threadIdx.x;
        int tl = g >> 3;             // 0..63  t row
        int cj = (g & 7) << 3;       // 0..56  c col (x8)
        unsigned short tmp[8];
#pragma unroll
        for (int i = 0; i < 8; ++i) {
            __hip_bfloat16 h = __float2bfloat16(tile[cj + i][tl]);
            tmp[i] = *reinterpret_cast<unsigned short*>(&h);
        }
        *reinterpret_cast<short8*>(xtb + (size_t)tl * C_ + cj) =
            *reinterpret_cast<const short8*>(tmp);
    }
}

// ---------------- conv-as-GEMM: out[b][o][t] = sum_n Wb[n] @ xT(shifted) + bias ----------------
__global__ __launch_bounds__(256, 2) void conv_gemm_kernel(
        const unsigned short* __restrict__ wb,
        const unsigned short* __restrict__ xt,
        const float* __restrict__ bias,
        float* __restrict__ out) {
    __shared__ unsigned short a_lds[KT * BM * AST];   // [tap][o_row][c]
    __shared__ unsigned short b_lds[(BN + 4) * BST];  // [t_row][c], t_row r <-> t = t0-2+r

    int b   = blockIdx.z;
    int o0  = blockIdx.y * BM;
    int t0  = blockIdx.x * BN;
    int tid = threadIdx.x;
    int lane = tid & 63;
    int wid  = tid >> 6;
    int wm = wid >> 1;        // 0..1  (wave row in 2x2 wave grid)
    int wn = wid & 1;         // 0..1
    int lr = lane & 15;       // 0..15
    int lg = lane >> 4;       // 0..3

    f32x4 acc[4][4];
#pragma unroll
    for (int mi = 0; mi < 4; ++mi)
#pragma unroll
        for (int ni = 0; ni < 4; ++ni)
            acc[mi][ni] = (f32x4)0.0f;

    for (int chunk = 0; chunk < NCHUNK; ++chunk) {
        int c0 = chunk * BK;

        // ---- stage A: 5 taps x 128 rows x 32 c = 2560 groups of 8 bf16 (10 iters x 256 thr)
#pragma unroll
        for (int it = 0; it < 10; ++it) {
            int g  = it * 256 + tid;
            int e0 = g * 8;
            int n  = e0 >> 12;            // /4096 (=128*32)
            int r  = (e0 & 4095) >> 5;    // /32
            int ci = e0 & 31;             // 0,8,16,24
            int4v v = *reinterpret_cast<const int4v*>(
                wb + ((size_t)(n * O_ + o0 + r)) * C_ + c0 + ci);
            *reinterpret_cast<int4v*>(&a_lds[(n * BM + r) * AST + ci]) = v;
        }
        // ---- stage B: 132 rows x 32 c = 528 groups of 8 bf16
        for (int g = tid; g < (BN + 4) * (BK / 8); g += 256) {
            int r  = g >> 2;
            int ci = (g & 3) << 3;
            int t  = t0 - 2 + r;
            int4v v = {0, 0, 0, 0};
            if (t >= 0 && t < T_)
                v = *reinterpret_cast<const int4v*>(
                    xt + ((size_t)b * T_ + t) * C_ + c0 + ci);
            *reinterpret_cast<int4v*>(&b_lds[r * BST + ci]) = v;
        }
        __syncthreads();

        // ---- compute: for each tap, 4x4 MFMA tiles of 16x16x32
#pragma unroll
        for (int n = 0; n < KT; ++n) {
            short8 af[4], bf[4];
#pragma unroll
            for (int mi = 0; mi < 4; ++mi)
                af[mi] = *reinterpret_cast<const short8*>(
                    &a_lds[(n * BM + wm * 64 + mi * 16 + lr) * AST + lg * 8]);
#pragma unroll
            for (int ni = 0; ni < 4; ++ni)
                bf[ni] = *reinterpret_cast<const short8*>(
                    &b_lds[(wn * 64 + ni * 16 + lr + 4 - n) * BST + lg * 8]);
#pragma unroll
            for (int mi = 0; mi < 4; ++mi)
#pragma unroll
                for (int ni = 0; ni < 4; ++ni)
                    acc[mi][ni] = __builtin_amdgcn_mfma_f32_16x16x32_bf16(
                        af[mi], bf[ni], acc[mi][ni], 0, 0, 0);
        }
        __syncthreads();
    }

    // ---- epilogue: C/D layout col=lane&15, row=(lane>>4)*4+reg (m89-verified)
#pragma unroll
    for (int mi = 0; mi < 4; ++mi) {
#pragma unroll
        for (int ni = 0; ni < 4; ++ni) {
            int orow = o0 + wm * 64 + mi * 16 + lg * 4;
            int tcol = t0 + wn * 64 + ni * 16 + lr;
#pragma unroll
            for (int r = 0; r < 4; ++r) {
                out[((size_t)b * O_ + orow + r) * T_ + tcol] =
                    acc[mi][ni][r] + bias[orow + r];
            }
        }
    }
}

extern "C" void kernel_launch(void* const* d_in, const int* in_sizes, int n_in,
                              void* d_out, int out_size, void* d_ws, size_t ws_size,
                              hipStream_t stream) {
    const float* x    = (const float*)d_in[0];
    const float* w    = (const float*)d_in[1];
    const float* bias = (const float*)d_in[2];
    float* out        = (float*)d_out;

    unsigned short* wb = (unsigned short*)d_ws;                 // 5*512*512 bf16 = 2.62 MB
    unsigned short* xtp = wb + (size_t)KT * O_ * C_;            // 16*4096*512 bf16 = 64 MB

    wrepack_kernel<<<(KT * O_ * C_ + 255) / 256, 256, 0, stream>>>(w, wb);
    xtrans_kernel<<<dim3(T_ / 64, C_ / 64, B_), 256, 0, stream>>>(x, xtp);
    conv_gemm_kernel<<<dim3(T_ / BN, O_ / BM, B_), 256, 0, stream>>>(wb, xtp, bias, out);
}

// Round 2
// 231.960 us; speedup vs baseline: 1.0147x; 1.0147x over previous
//
#include <hip/hip_runtime.h>
#include <hip/hip_bf16.h>

typedef __attribute__((ext_vector_type(8))) short short8;
typedef __attribute__((ext_vector_type(4))) float f32x4;

#define B_   16
#define O_   512
#define C_   512
#define T_   4096
#define TP   (T_ + 32)     // padded t extent: 16 zero rows each side
#define KT   5
#define BM   128
#define BN   128
#define BK   32
#define NCHUNK (C_/BK)

__device__ __forceinline__ void gload_lds16(const void* g, void* l) {
    __builtin_amdgcn_global_load_lds(
        (const __attribute__((address_space(1))) unsigned int*)g,
        (__attribute__((address_space(3))) unsigned int*)l, 16, 0, 0);
}

// ---------------- weight repack: w[o][c][n] f32 -> Wb[n][o][c] bf16 ----------------
__global__ void wrepack_kernel(const float* __restrict__ w, unsigned short* __restrict__ wb) {
    int e = blockIdx.x * 256 + threadIdx.x;
    if (e >= KT * O_ * C_) return;
    int n   = e / (O_ * C_);
    int rem = e % (O_ * C_);
    int o   = rem / C_;
    int c   = rem % C_;
    float v = w[((size_t)o * C_ + c) * KT + n];
    __hip_bfloat16 h = __float2bfloat16(v);
    wb[e] = *reinterpret_cast<unsigned short*>(&h);
}

// ---------------- zero the pad rows of xT ----------------
__global__ void padzero_kernel(unsigned short* __restrict__ xt) {
    int i = blockIdx.x * 256 + threadIdx.x;
    if (i >= B_ * 32 * C_) return;
    int b = i / (32 * C_);
    int r = (i / C_) % 32;
    int c = i % C_;
    int tp = (r < 16) ? r : (T_ + r);   // [0,16) and [T_+16, T_+32)
    xt[((size_t)b * TP + tp) * C_ + c] = 0;
}

// ---------------- x transpose: x[b][c][t] f32 -> xT[b][16+t][c] bf16 ----------------
__global__ void xtrans_kernel(const float* __restrict__ x, unsigned short* __restrict__ xt) {
    __shared__ float tile[64][65];
    int b  = blockIdx.z;
    int c0 = blockIdx.y * 64;
    int t0 = blockIdx.x * 64;
    const float* xb = x + ((size_t)b * C_ + c0) * T_ + t0;
#pragma unroll
    for (int p = 0; p < 4; ++p) {
        int idx = p * 256 + threadIdx.x;
        int cl = idx >> 4;
        int tj = (idx & 15) << 2;
        float4 v = *reinterpret_cast<const float4*>(xb + (size_t)cl * T_ + tj);
        tile[cl][tj + 0] = v.x;
        tile[cl][tj + 1] = v.y;
        tile[cl][tj + 2] = v.z;
        tile[cl][tj + 3] = v.w;
    }
    __syncthreads();
    unsigned short* xtb = xt + ((size_t)b * TP + 16 + t0) * C_ + c0;
#pragma unroll
    for (int p = 0; p < 2; ++p) {
        int g  = p * 256 + threadIdx.x;
        int tl = g >> 3;
        int cj = (g & 7) << 3;
        unsigned short tmp[8];
#pragma unroll
        for (int i = 0; i < 8; ++i) {
            __hip_bfloat16 h = __float2bfloat16(tile[cj + i][tl]);
            tmp[i] = *reinterpret_cast<unsigned short*>(&h);
        }
        *reinterpret_cast<short8*>(xtb + (size_t)tl * C_ + cj) =
            *reinterpret_cast<const short8*>(tmp);
    }
}

// ---------------- conv-as-GEMM ----------------
// A: fragment-major LDS, 40 frags (5 taps x 8 rowblks) x 1024B, zero-conflict reads.
// B: row-major [144][32] with XOR slot swizzle, staged via pre-swizzled global src.
__global__ __launch_bounds__(256, 3) void conv_gemm_kernel(
        const unsigned short* __restrict__ wb,
        const unsigned short* __restrict__ xt,
        const float* __restrict__ bias,
        float* __restrict__ out) {
    __shared__ unsigned short a_lds[KT * 8 * 512];   // 40960 B
    __shared__ unsigned short b_lds[144 * 32];       // 9216 B

    int b   = blockIdx.z;
    int o0  = blockIdx.y * BM;
    int t0  = blockIdx.x * BN;
    int tid = threadIdx.x;
    int lane = tid & 63;
    int wid  = tid >> 6;
    int wm = wid >> 1;
    int wn = wid & 1;
    int lr = lane & 15;
    int lg = lane >> 4;

    // per-lane B read offsets (ushort units), chunk-invariant:
    // row = wn*64 + ni*16 + lr + 4 - n ; swizzled slot = lg ^ ((row>>1)&3)
    int bo[KT][4];
#pragma unroll
    for (int n = 0; n < KT; ++n)
#pragma unroll
        for (int ni = 0; ni < 4; ++ni) {
            int row = wn * 64 + ni * 16 + lr + 4 - n;
            bo[n][ni] = row * 32 + ((lg ^ ((row >> 1) & 3)) << 3);
        }

    f32x4 acc[4][4];
#pragma unroll
    for (int mi = 0; mi < 4; ++mi)
#pragma unroll
        for (int ni = 0; ni < 4; ++ni)
            acc[mi][ni] = (f32x4)0.0f;

    // per-lane global staging bases
    const unsigned short* ag = wb + ((size_t)(o0 + lr)) * C_ + lg * 8;
    // B: lane l stages (row = 16j + (l>>2), slot = l&3) from logical c8 = slot ^ ((row>>1)&3)
    //    = (l&3) ^ ((l>>3)&3)  (j*16 contributes 0 mod 8)
    int c8 = (lane & 3) ^ ((lane >> 3) & 3);
    const unsigned short* bg = xt + ((size_t)b * TP + (t0 + 14 + (lane >> 2))) * C_ + c8 * 8;

    for (int chunk = 0; chunk < NCHUNK; ++chunk) {
        int c0 = chunk * BK;

        // ---- stage A: 40 fragment loads, 10 per wave
#pragma unroll
        for (int f = wid; f < 40; f += 4) {
            int n  = f >> 3;
            int rb = f & 7;
            gload_lds16(ag + ((size_t)(n * O_ + rb * 16)) * C_ + c0, &a_lds[f * 512]);
        }
        // ---- stage B: 9 row-group loads (144 rows x 64B)
#pragma unroll
        for (int j = wid; j < 9; j += 4) {
            gload_lds16(bg + (size_t)(j * 16) * C_ + c0, &b_lds[j * 512]);
        }
        __syncthreads();

        // ---- compute
#pragma unroll
        for (int n = 0; n < KT; ++n) {
            short8 af[4], bf[4];
#pragma unroll
            for (int mi = 0; mi < 4; ++mi)
                af[mi] = *reinterpret_cast<const short8*>(
                    &a_lds[(n * 8 + wm * 4 + mi) * 512 + lane * 8]);
#pragma unroll
            for (int ni = 0; ni < 4; ++ni)
                bf[ni] = *reinterpret_cast<const short8*>(&b_lds[bo[n][ni]]);
#pragma unroll
            for (int mi = 0; mi < 4; ++mi)
#pragma unroll
                for (int ni = 0; ni < 4; ++ni)
                    acc[mi][ni] = __builtin_amdgcn_mfma_f32_16x16x32_bf16(
                        af[mi], bf[ni], acc[mi][ni], 0, 0, 0);
        }
        __syncthreads();
    }

    // ---- epilogue: C/D layout col=lane&15, row=(lane>>4)*4+reg
#pragma unroll
    for (int mi = 0; mi < 4; ++mi) {
#pragma unroll
        for (int ni = 0; ni < 4; ++ni) {
            int orow = o0 + wm * 64 + mi * 16 + lg * 4;
            int tcol = t0 + wn * 64 + ni * 16 + lr;
#pragma unroll
            for (int r = 0; r < 4; ++r) {
                out[((size_t)b * O_ + orow + r) * T_ + tcol] =
                    acc[mi][ni][r] + bias[orow + r];
            }
        }
    }
}

extern "C" void kernel_launch(void* const* d_in, const int* in_sizes, int n_in,
                              void* d_out, int out_size, void* d_ws, size_t ws_size,
                              hipStream_t stream) {
    const float* x    = (const float*)d_in[0];
    const float* w    = (const float*)d_in[1];
    const float* bias = (const float*)d_in[2];
    float* out        = (float*)d_out;

    unsigned short* wb  = (unsigned short*)d_ws;            // 2.62 MB
    unsigned short* xtp = wb + (size_t)KT * O_ * C_;        // 16*4128*512 bf16 = 67.7 MB

    padzero_kernel<<<(B_ * 32 * C_ + 255) / 256, 256, 0, stream>>>(xtp);
    wrepack_kernel<<<(KT * O_ * C_ + 255) / 256, 256, 0, stream>>>(w, wb);
    xtrans_kernel<<<dim3(T_ / 64, C_ / 64, B_), 256, 0, stream>>>(x, xtp);
    conv_gemm_kernel<<<dim3(T_ / BN, O_ / BM, B_), 256, 0, stream>>>(wb, xtp, bias, out);
}